// Round 6
// baseline (232.530 us; speedup 1.0000x reference)
//
#include <hip/hip_runtime.h>
#include <stdint.h>

typedef __attribute__((ext_vector_type(4))) int i32x4;

#define N_FRAMES 16386
#define D_DIM    1024
#define O_DIM    2048
#define L_CTX    3
#define K_DIM    3072   // D_DIM * L_CTX
#define T_DIM    16384  // N_FRAMES - L_CTX + 1
#define NKT      24     // K_DIM / 128  (128-byte K-tiles)

// workspace byte offsets
#define WS_MM     0u
#define WS_PARAMS 64u
#define WS_CO     256u
#define WS_S      16384u
#define WS_CT     98304u
#define WS_QW     262144u
#define WS_QX     8388608u

struct Params {
  float w_scale, in_scale, cscale;
  int   w_zp, in_zp, konst;
};

typedef __attribute__((address_space(3))) void       lds_void;
typedef const __attribute__((address_space(1))) void gbl_void;

__device__ __forceinline__ unsigned flip_f(float f) {
  unsigned u = __float_as_uint(f);
  return (u & 0x80000000u) ? ~u : (u | 0x80000000u);
}
__device__ __forceinline__ float unflip_f(unsigned v) {
  unsigned u = (v & 0x80000000u) ? (v ^ 0x80000000u) : ~v;
  return __uint_as_float(u);
}

__global__ void init_kernel(unsigned* mm) {
  mm[0] = 0xFFFFFFFFu;
  mm[1] = 0u;
}

__global__ __launch_bounds__(256) void wminmax_kernel(const float4* __restrict__ w,
                                                      unsigned* mm, int n4) {
  unsigned lmin = 0xFFFFFFFFu, lmax = 0u;
  for (int i = blockIdx.x * blockDim.x + threadIdx.x; i < n4; i += gridDim.x * blockDim.x) {
    float4 v = w[i];
    unsigned a = flip_f(v.x), b = flip_f(v.y), c = flip_f(v.z), d = flip_f(v.w);
    lmin = min(lmin, min(min(a, b), min(c, d)));
    lmax = max(lmax, max(max(a, b), max(c, d)));
  }
#pragma unroll
  for (int off = 32; off > 0; off >>= 1) {
    lmin = min(lmin, (unsigned)__shfl_xor((int)lmin, off, 64));
    lmax = max(lmax, (unsigned)__shfl_xor((int)lmax, off, 64));
  }
  if ((threadIdx.x & 63) == 0) {
    atomicMin(&mm[0], lmin);
    atomicMax(&mm[1], lmax);
  }
}

__global__ void params_kernel(const unsigned* __restrict__ mm,
                              const float* __restrict__ in_min,
                              const float* __restrict__ in_max,
                              Params* __restrict__ p) {
  float wmin = unflip_f(mm[0]);
  float wmax = unflip_f(mm[1]);
  float ws = (wmax - wmin) / 254.0f;
  float wz = -127.0f - wmin / ws;
  wz = fminf(fmaxf(wz, -127.0f), 127.0f);
  int wzp = (int)wz;
  float imin = *in_min, imax = *in_max;
  float is = (imax - imin) / 254.0f;
  float iz = -127.0f - imin / is;
  iz = fminf(fmaxf(iz, -127.0f), 127.0f);
  int izp = (int)iz;
  p->w_scale = ws; p->in_scale = is; p->cscale = is * ws;
  p->w_zp = wzp;   p->in_zp = izp;
  p->konst = K_DIM * wzp * izp;
}

__global__ __launch_bounds__(256) void quantw_kernel(
    const float* __restrict__ w, const float* __restrict__ bias,
    const Params* __restrict__ p, int8_t* __restrict__ qw,
    int* __restrict__ co, float* __restrict__ dq, float* __restrict__ bias_out) {
  const int o = blockIdx.x;
  const float ws = p->w_scale;
  const float zpf = (float)p->w_zp;
  const float* wrow = w + (size_t)o * K_DIM;
  float* dqrow = dq + (size_t)o * K_DIM;
  int8_t* qrow = qw + (size_t)o * K_DIM;
  int sum = 0;
#pragma unroll
  for (int pass = 0; pass < 3; ++pass) {
    const int k = (pass << 10) + (threadIdx.x << 2);
    float4 v = *(const float4*)(wrow + k);
    int8_t c0 = (int8_t)(int)rintf(v.x / ws + zpf);
    int8_t c1 = (int8_t)(int)rintf(v.y / ws + zpf);
    int8_t c2 = (int8_t)(int)rintf(v.z / ws + zpf);
    int8_t c3 = (int8_t)(int)rintf(v.w / ws + zpf);
    sum += (int)c0 + (int)c1 + (int)c2 + (int)c3;
    unsigned packed = (unsigned)(uint8_t)c0 | ((unsigned)(uint8_t)c1 << 8)
                    | ((unsigned)(uint8_t)c2 << 16) | ((unsigned)(uint8_t)c3 << 24);
    *(unsigned*)(qrow + k) = packed;
    float4 d;
    d.x = ((float)c0 - zpf) * ws;
    d.y = ((float)c1 - zpf) * ws;
    d.z = ((float)c2 - zpf) * ws;
    d.w = ((float)c3 - zpf) * ws;
    *(float4*)(dqrow + k) = d;
  }
  __shared__ int red[4];
#pragma unroll
  for (int off = 32; off > 0; off >>= 1) sum += __shfl_xor(sum, off, 64);
  if ((threadIdx.x & 63) == 0) red[threadIdx.x >> 6] = sum;
  __syncthreads();
  if (threadIdx.x == 0) {
    int tot = red[0] + red[1] + red[2] + red[3];
    co[o] = -p->in_zp * tot;
    bias_out[o] = bias[o];
  }
}

__global__ __launch_bounds__(256) void quantx_kernel(
    const float* __restrict__ x, const Params* __restrict__ p,
    int8_t* __restrict__ qx, int* __restrict__ s) {
  const int n = blockIdx.x;
  const float is = p->in_scale;
  const float zpf = (float)p->in_zp;
  const float4 v = *((const float4*)(x + (size_t)n * D_DIM) + threadIdx.x);
  int8_t c0 = (int8_t)(int)rintf(v.x / is + zpf);
  int8_t c1 = (int8_t)(int)rintf(v.y / is + zpf);
  int8_t c2 = (int8_t)(int)rintf(v.z / is + zpf);
  int8_t c3 = (int8_t)(int)rintf(v.w / is + zpf);
  unsigned packed = (unsigned)(uint8_t)c0 | ((unsigned)(uint8_t)c1 << 8)
                  | ((unsigned)(uint8_t)c2 << 16) | ((unsigned)(uint8_t)c3 << 24);
  ((unsigned*)(qx + (size_t)n * D_DIM))[threadIdx.x] = packed;
  int sum = (int)c0 + (int)c1 + (int)c2 + (int)c3;
  __shared__ int red[4];
#pragma unroll
  for (int off = 32; off > 0; off >>= 1) sum += __shfl_xor(sum, off, 64);
  if ((threadIdx.x & 63) == 0) red[threadIdx.x >> 6] = sum;
  __syncthreads();
  if (threadIdx.x == 0) s[n] = red[0] + red[1] + red[2] + red[3];
}

__global__ __launch_bounds__(256) void ct_kernel(const int* __restrict__ s,
                                                 const Params* __restrict__ p,
                                                 int* __restrict__ ct) {
  const int t = blockIdx.x * blockDim.x + threadIdx.x;
  if (t < T_DIM) ct[t] = p->konst - p->w_zp * (s[t] + s[t + 1] + s[t + 2]);
}

// int8 NT GEMM, 256x128 tile, 4 waves (2x2, per-wave 128x64), 128B K-tiles.
// A via LDS (2x32KB dbuf, swizzled, global_load_lds); B direct global->reg
// (double-buffered, per-wave counted vmcnt). 2 blocks/CU co-resident (64KB LDS)
// give cross-block pipe overlap; 2 barriers per K-tile; rolling per-m A-frag
// ds_read under MFMA stream (fine DS||VMEM||MFMA interleave).

#define KT_MFMA(ktc, BUF, BCUR, BNXT)                                          \
  {                                                                            \
    _Pragma("unroll")                                                          \
    for (int m = 0; m < 8; ++m) {                                              \
      if (m == 0 && (ktc) + 1 < NKT) {                                         \
        _Pragma("unroll")                                                      \
        for (int n = 0; n < 4; ++n) {                                          \
          BNXT[n][0] = *(const i32x4*)(qwB[n] + (((ktc) + 1) << 7));           \
          BNXT[n][1] = *(const i32x4*)(qwB[n] + (((ktc) + 1) << 7) + 64);      \
        }                                                                      \
      }                                                                        \
      if (m < 7) {                                                             \
        aF[(m + 1) & 1][0] = *(const i32x4*)&A_lds[BUF][aBase + ((m + 1) << 11) + c00]; \
        aF[(m + 1) & 1][1] = *(const i32x4*)&A_lds[BUF][aBase + ((m + 1) << 11) + c01]; \
      }                                                                        \
      _Pragma("unroll")                                                        \
      for (int n = 0; n < 4; ++n) {                                            \
        acc[m][n] = __builtin_amdgcn_mfma_i32_16x16x64_i8(aF[m & 1][0], BCUR[n][0], acc[m][n], 0, 0, 0); \
        acc[m][n] = __builtin_amdgcn_mfma_i32_16x16x64_i8(aF[m & 1][1], BCUR[n][1], acc[m][n], 0, 0, 0); \
      }                                                                        \
    }                                                                          \
  }

#define KT_TAIL(ktc, BUF)                                                      \
  {                                                                            \
    asm volatile("" ::: "memory");                                             \
    __builtin_amdgcn_s_barrier();                                              \
    if ((ktc) + 2 < NKT) stageA(BUF, (ktc) + 2);                               \
    if ((ktc) + 2 < NKT) {                                                     \
      asm volatile("s_waitcnt vmcnt(8)" ::: "memory");                         \
    } else if ((ktc) + 1 < NKT) {                                              \
      asm volatile("s_waitcnt vmcnt(0)" ::: "memory");                         \
    }                                                                          \
    __builtin_amdgcn_s_barrier();                                              \
    if ((ktc) + 1 < NKT) {                                                     \
      aF[0][0] = *(const i32x4*)&A_lds[(BUF) ^ 1][aBase + c00];                \
      aF[0][1] = *(const i32x4*)&A_lds[(BUF) ^ 1][aBase + c01];                \
    }                                                                          \
  }

__global__ __launch_bounds__(256, 2) void gemm_kernel(
    const int8_t* __restrict__ qx, const int8_t* __restrict__ qw,
    const int* __restrict__ co, const int* __restrict__ ct,
    const float* __restrict__ bias, const Params* __restrict__ p,
    float* __restrict__ out) {
  __shared__ int8_t A_lds[2][256 * 128];   // 32 KB per buf, A only

  const int bid = blockIdx.x;
  const int tm = bid & 63;   // 16 blocks sharing an A-panel share bid%8 -> same XCD
  const int tn = bid >> 6;
  const int m0 = tm << 8, n0 = tn << 7;
  const int tid = threadIdx.x;
  const int lane = tid & 63, wave = tid >> 6;
  const int wm = wave >> 1, wn = wave & 1;   // 2x2 wave grid, per-wave 128x64
  const int lr = lane & 15, kg = lane >> 4;
  const int lr7 = lane & 7;

  // A staging: per wave 8 events of 1KB (8 rows x 128B each); event j covers
  // LDS rows (j*4+wave)*8..+8. Source chunk pre-swizzled with ^(row&7).
  const int erow = lane >> 3;
  const int esc  = ((lane & 7) ^ erow) << 4;
  const int8_t* qxa = qx + (size_t)(m0 + (wave << 3) + erow) * D_DIM + esc;

  // B direct-load bases: frag n = rows n0+wn*64+n*16+lr, lane chunk kg*16
  const int8_t* qwB[4];
#pragma unroll
  for (int n = 0; n < 4; ++n)
    qwB[n] = qw + (size_t)(n0 + (wn << 6) + (n << 4) + lr) * K_DIM + (kg << 4);

  // A fragment read: row = wm*128 + m*16 + lr; phys chunk = (ks*4+kg)^(row&7)
  const int aBase = ((wm << 7) + lr) << 7;
  const int c00 = (kg ^ lr7) << 4;
  const int c01 = c00 ^ 64;

  i32x4 aF[2][2], bE[4][2], bO[4][2];
  i32x4 acc[8][4] = {};

  auto stageA = [&](int buf, int kt) {
#pragma unroll
    for (int j = 0; j < 8; ++j)
      __builtin_amdgcn_global_load_lds(
          (gbl_void*)(qxa + (kt << 7) + (size_t)(j << 5) * D_DIM),
          (lds_void*)(&A_lds[buf][(j << 12) + (wave << 10)]), 16, 0, 0);
  };

  // prologue: stage A(0); load B(0); stage A(1); wait A(0)+B(0) (A(1) flies)
  stageA(0, 0);
#pragma unroll
  for (int n = 0; n < 4; ++n) {
    bE[n][0] = *(const i32x4*)(qwB[n]);
    bE[n][1] = *(const i32x4*)(qwB[n] + 64);
  }
  stageA(1, 1);
  asm volatile("s_waitcnt vmcnt(8)" ::: "memory");
  __builtin_amdgcn_s_barrier();
  aF[0][0] = *(const i32x4*)&A_lds[0][aBase + c00];
  aF[0][1] = *(const i32x4*)&A_lds[0][aBase + c01];

  for (int kt = 0; kt < NKT; kt += 2) {
    KT_MFMA(kt, 0, bE, bO);
    KT_TAIL(kt, 0);
    KT_MFMA(kt + 1, 1, bO, bE);
    KT_TAIL(kt + 1, 1);
  }

  // epilogue: dequant + zero-point correction + bias
  const float cscale = p->cscale;
  int   cov[4];
  float bov[4];
#pragma unroll
  for (int n = 0; n < 4; ++n) {
    const int o_ = n0 + (wn << 6) + (n << 4) + lr;
    cov[n] = co[o_];
    bov[n] = bias[o_];
  }
#pragma unroll
  for (int m = 0; m < 8; ++m) {
    const int tbase = m0 + (wm << 7) + (m << 4) + (kg << 2);
    int ctv[4];
#pragma unroll
    for (int r = 0; r < 4; ++r) ctv[r] = ct[tbase + r];
#pragma unroll
    for (int n = 0; n < 4; ++n) {
      const int o_ = n0 + (wn << 6) + (n << 4) + lr;
#pragma unroll
      for (int r = 0; r < 4; ++r) {
        out[(size_t)(tbase + r) * O_DIM + o_] =
            (float)(acc[m][n][r] + cov[n] + ctv[r]) * cscale + bov[n];
      }
    }
  }
}

extern "C" void kernel_launch(void* const* d_in, const int* in_sizes, int n_in,
                              void* d_out, int out_size, void* d_ws, size_t ws_size,
                              hipStream_t stream) {
  const float* x      = (const float*)d_in[0];
  const float* w      = (const float*)d_in[1];
  const float* bias   = (const float*)d_in[2];
  const float* in_min = (const float*)d_in[3];
  const float* in_max = (const float*)d_in[4];
  float* out = (float*)d_out;

  uint8_t* ws = (uint8_t*)d_ws;
  unsigned* mm = (unsigned*)(ws + WS_MM);
  Params*   prm = (Params*)(ws + WS_PARAMS);
  int*      co = (int*)(ws + WS_CO);
  int*      s  = (int*)(ws + WS_S);
  int*      ct = (int*)(ws + WS_CT);
  int8_t*   qw = (int8_t*)(ws + WS_QW);
  int8_t*   qx = (int8_t*)(ws + WS_QX);

  float* dq_out   = out + (size_t)T_DIM * O_DIM;
  float* bias_out = dq_out + (size_t)O_DIM * K_DIM;

  init_kernel<<<1, 1, 0, stream>>>(mm);
  wminmax_kernel<<<512, 256, 0, stream>>>((const float4*)w, mm, O_DIM * K_DIM / 4);
  params_kernel<<<1, 1, 0, stream>>>(mm, in_min, in_max, prm);
  quantw_kernel<<<O_DIM, 256, 0, stream>>>(w, bias, prm, qw, co, dq_out, bias_out);
  quantx_kernel<<<N_FRAMES, 256, 0, stream>>>(x, prm, qx, s);
  ct_kernel<<<T_DIM / 256, 256, 0, stream>>>(s, prm, ct);
  gemm_kernel<<<(T_DIM / 256) * (O_DIM / 128), 256, 0, stream>>>(qx, qw, co, ct, bias, prm, out);
}